// Round 4
// baseline (1313.506 us; speedup 1.0000x reference)
//
#include <hip/hip_runtime.h>

// ---------------------------------------------------------------------------
// TemporalHeteroConv on MI355X.  N=100000 nodes, E=800000 edges, C=64, H=4.
// r12: fix r11b's two regressions.
//  (a) colscan was 13-block/391-serial-iter latency disaster -> two-level
//      tile scan: k_cs1 (169 blocks, 32 coalesced iters) + k_cs2 (13 iters);
//      tile base folded into k_fill2 cursor init.
//  (b) k_aggb's per-node depth-2 loop was gather-latency-bound (105us) ->
//      sort-free LDS-atomic version: stage records, 4-group/4-prefetch edge
//      pipeline (verified r6 pattern, 8 gathers in flight), accumulate into
//      accL[node][h][c] via ds_add_f32 (stride-4B lanes = conflict-free).
// Pipeline:
//   k_init   : Pw B-frags + Wt A-frags + per-chunk LDS bin histograms.
//   k_hd     : node-only MFMA GEMM h16|u|v (verified r10 path).
//   k_cs1/2  : chunk-prefix over histM (in-place) + tile totals scan.
//   scan1/2  : (verified) exclusive scan of bintot -> offsb/bsumsb.
//   k_fill2  : score + binned placement via LDS cursors, 16B record/edge.
//   k_aggb   : block/bin LDS-atomic aggregation (above), agg layout [n][c][h].
//   k_projm  : MFMA proj GEMM + LN/residual/ReLU epilogue (untouched).
// ---------------------------------------------------------------------------

typedef __attribute__((ext_vector_type(8))) short bf16x8;
typedef __attribute__((ext_vector_type(4))) float f32x4;

#define CHUNK  2048          // edges per histogram/scatter block
#define BINSH  5             // 32 nodes per bin
#define BINSZ  32
#define MAXBIN 3200          // >= ceil(102400/32)
#define MAXREC 1024          // Poisson(256): P(cnt>1024) ~ 0
#define CTW    32            // chunks per scan tile

__device__ __forceinline__ unsigned short f2bf(float f) {
  unsigned int u = __float_as_uint(f);
  u += 0x7FFFu + ((u >> 16) & 1u);          // RNE
  return (unsigned short)(u >> 16);
}
__device__ __forceinline__ float bf2f(unsigned short s) {
  return __uint_as_float(((unsigned int)s) << 16);
}
__device__ __forceinline__ unsigned int pk(float a, float b) {
  return (unsigned int)f2bf(a) | ((unsigned int)f2bf(b) << 16);
}
__device__ __forceinline__ float bflo(int u) {
  return __uint_as_float(((unsigned int)u) << 16);
}
__device__ __forceinline__ float bfhi(int u) {
  return __uint_as_float(((unsigned int)u) & 0xFFFF0000u);
}

// split 8 fp32 into bf16 hi + bf16 lo(residual) fragments
__device__ __forceinline__ void split8(float4 a, float4 b, bf16x8* hi, bf16x8* lo) {
  float f[8] = {a.x, a.y, a.z, a.w, b.x, b.y, b.z, b.w};
  bf16x8 h, l;
  #pragma unroll
  for (int j = 0; j < 8; ++j) {
    unsigned short hs = f2bf(f[j]);
    h[j] = (short)hs;
    l[j] = (short)f2bf(f[j] - bf2f(hs));
  }
  *hi = h; *lo = l;
}

// ------- init: Bf pack (b<64) + Wt A-frags (b==64) + edge histograms -------
__global__ __launch_bounds__(256) void k_init(const float* __restrict__ Pw,
    const float* __restrict__ Ww, const float* __restrict__ Wb,
    const float* __restrict__ aw, const int* __restrict__ ei,
    unsigned short* __restrict__ Bf, unsigned short* __restrict__ Ah,
    unsigned short* __restrict__ Al, float* __restrict__ bc,
    int* __restrict__ histM, int E, int NBIN)
{
  __shared__ int hist[MAXBIN];
  const int b = blockIdx.x;
  if (b < 64) {                      // ---- Pw -> bf16 B-fragment order ----
    int i = b * 256 + threadIdx.x;   // i < 16384
    int j    = i & 7;
    int lane = (i >> 3) & 63;
    int cb   = (i >> 9) & 3;
    int ks   = i >> 11;
    int k    = ks * 32 + (lane >> 4) * 8 + j;
    int colg = cb * 16 + (lane & 15);
    Bf[i] = f2bf(Pw[(size_t)k * 64 + colg]);
    return;
  }
  if (b == 64) {                     // ---- combined Wt(80x64) A-frags ----
    int t = threadIdx.x;
    for (int i = t; i < 5120; i += 256) {
      int j = i & 7, lane = (i >> 3) & 63, ks = (i >> 9) & 1, rb = i >> 10;
      int row = rb * 16 + (lane & 15);
      int k   = ks * 32 + (lane >> 4) * 8 + j;
      float w = 0.f;
      if (row < 64) {
        w = Ww[(size_t)k * 64 + row];
      } else if (row < 72) {
        int jj = row - 64;
        const float* ac = (jj < 4) ? (aw + jj) : (aw + 256 + (jj - 4));
        float s = 0.f;
        for (int c = 0; c < 64; ++c) s = fmaf(Ww[(size_t)k * 64 + c], ac[c * 4], s);
        w = s;
      }
      unsigned short hh = f2bf(w);
      Ah[i] = hh;
      Al[i] = f2bf(w - bf2f(hh));
    }
    if (t < 80) {
      float bb = 0.f;
      if (t < 64) {
        bb = Wb[t];
      } else if (t < 72) {
        int jj = t - 64;
        const float* ac = (jj < 4) ? (aw + jj) : (aw + 256 + (jj - 4));
        float s = 0.f;
        for (int c = 0; c < 64; ++c) s = fmaf(Wb[c], ac[c * 4], s);
        bb = s;
      }
      bc[t] = bb;
    }
    return;
  }
  // ---- per-chunk bin histogram (LDS atomics only) ----
  const int cb = b - 65;
  for (int i = threadIdx.x; i < NBIN; i += 256) hist[i] = 0;
  __syncthreads();
  const int base = cb * CHUNK + threadIdx.x * 8;
  const int* dptr = ei + E;
  if (base + 7 < E) {
    int4 d0 = *(const int4*)(dptr + base);
    int4 d1 = *(const int4*)(dptr + base + 4);
    atomicAdd(&hist[d0.x >> BINSH], 1);
    atomicAdd(&hist[d0.y >> BINSH], 1);
    atomicAdd(&hist[d0.z >> BINSH], 1);
    atomicAdd(&hist[d0.w >> BINSH], 1);
    atomicAdd(&hist[d1.x >> BINSH], 1);
    atomicAdd(&hist[d1.y >> BINSH], 1);
    atomicAdd(&hist[d1.z >> BINSH], 1);
    atomicAdd(&hist[d1.w >> BINSH], 1);
  } else {
    for (int e = base; e < E; ++e) atomicAdd(&hist[dptr[e] >> BINSH], 1);
  }
  __syncthreads();
  for (int i = threadIdx.x; i < NBIN; i += 256)
    histM[(size_t)cb * NBIN + i] = hist[i];
}

// ------- node-only MFMA GEMM h|u|v (r10 path, verified) --------------------
#define RBSTEP(ACC, RB) { \
  bf16x8 fh0 = *(const bf16x8*)(Ah + ((RB * 2 + 0) * 64 + lane) * 8); \
  bf16x8 fl0 = *(const bf16x8*)(Al + ((RB * 2 + 0) * 64 + lane) * 8); \
  bf16x8 fh1 = *(const bf16x8*)(Ah + ((RB * 2 + 1) * 64 + lane) * 8); \
  bf16x8 fl1 = *(const bf16x8*)(Al + ((RB * 2 + 1) * 64 + lane) * 8); \
  ACC = __builtin_amdgcn_mfma_f32_16x16x32_bf16(fh0, bh0, ACC, 0, 0, 0); \
  ACC = __builtin_amdgcn_mfma_f32_16x16x32_bf16(fl0, bh0, ACC, 0, 0, 0); \
  ACC = __builtin_amdgcn_mfma_f32_16x16x32_bf16(fh0, bl0, ACC, 0, 0, 0); \
  ACC = __builtin_amdgcn_mfma_f32_16x16x32_bf16(fh1, bh1, ACC, 0, 0, 0); \
  ACC = __builtin_amdgcn_mfma_f32_16x16x32_bf16(fl1, bh1, ACC, 0, 0, 0); \
  ACC = __builtin_amdgcn_mfma_f32_16x16x32_bf16(fh1, bl1, ACC, 0, 0, 0); \
}

__global__ __launch_bounds__(256, 4) void k_hd(const float* __restrict__ x,
    const unsigned short* __restrict__ Ah, const unsigned short* __restrict__ Al,
    const float* __restrict__ bc, unsigned short* __restrict__ h16,
    float4* __restrict__ u, float4* __restrict__ v, int N)
{
  const int lane = threadIdx.x & 63;
  const int wv   = threadIdx.x >> 6;
  const int col  = lane & 15;
  const int quad = lane >> 4;

  const float4 bc0 = *(const float4*)(bc +  0 + quad * 4);
  const float4 bc1 = *(const float4*)(bc + 16 + quad * 4);
  const float4 bc2 = *(const float4*)(bc + 32 + quad * 4);
  const float4 bc3 = *(const float4*)(bc + 48 + quad * 4);
  const float4 bc4 = *(const float4*)(bc + 64 + quad * 4);

  const int base0 = blockIdx.x * 256 + wv * 64;
  for (int st = 0; st < 4; ++st) {
    const int node = base0 + st * 16 + col;
    const bool val = (node < N);
    const int nc = val ? node : N - 1;
    const float* xr = x + (size_t)nc * 64 + quad * 8;
    float4 x0 = *(const float4*)(xr);
    float4 x1 = *(const float4*)(xr + 4);
    float4 x2 = *(const float4*)(xr + 32);
    float4 x3 = *(const float4*)(xr + 36);
    bf16x8 bh0, bl0, bh1, bl1;
    split8(x0, x1, &bh0, &bl0);
    split8(x2, x3, &bh1, &bl1);

    f32x4 a0 = {0.f, 0.f, 0.f, 0.f};
    f32x4 a1 = {0.f, 0.f, 0.f, 0.f};
    f32x4 a2 = {0.f, 0.f, 0.f, 0.f};
    f32x4 a3 = {0.f, 0.f, 0.f, 0.f};
    f32x4 a4 = {0.f, 0.f, 0.f, 0.f};
    RBSTEP(a0, 0);
    RBSTEP(a1, 1);
    RBSTEP(a2, 2);
    RBSTEP(a3, 3);
    RBSTEP(a4, 4);

    if (val) {
      unsigned short* hr = h16 + (size_t)node * 64 + quad * 4;
      uint2 w0, w1, w2, w3;
      w0.x = pk(a0[0] + bc0.x, a0[1] + bc0.y);
      w0.y = pk(a0[2] + bc0.z, a0[3] + bc0.w);
      w1.x = pk(a1[0] + bc1.x, a1[1] + bc1.y);
      w1.y = pk(a1[2] + bc1.z, a1[3] + bc1.w);
      w2.x = pk(a2[0] + bc2.x, a2[1] + bc2.y);
      w2.y = pk(a2[2] + bc2.z, a2[3] + bc2.w);
      w3.x = pk(a3[0] + bc3.x, a3[1] + bc3.y);
      w3.y = pk(a3[2] + bc3.z, a3[3] + bc3.w);
      *(uint2*)(hr)      = w0;
      *(uint2*)(hr + 16) = w1;
      *(uint2*)(hr + 32) = w2;
      *(uint2*)(hr + 48) = w3;
      if (quad == 0)
        u[node] = make_float4(a4[0] + bc4.x, a4[1] + bc4.y, a4[2] + bc4.z, a4[3] + bc4.w);
      else if (quad == 1)
        v[node] = make_float4(a4[0] + bc4.x, a4[1] + bc4.y, a4[2] + bc4.z, a4[3] + bc4.w);
    }
  }
}

// ------- tile scan pass 1: in-place prefix over CTW chunks, coalesced ------
__global__ __launch_bounds__(256) void k_cs1(int* __restrict__ histM,
    int* __restrict__ tiletot, int NBIN, int NCH, int NBB)
{
  const int ct = blockIdx.x / NBB;
  const int bb = blockIdx.x - ct * NBB;
  const int bin = bb * 256 + threadIdx.x;
  if (bin >= NBIN) return;
  const int b0 = ct * CTW;
  const int b1 = min(b0 + CTW, NCH);
  int run = 0;
  for (int b = b0; b < b1; ++b) {
    size_t idx = (size_t)b * NBIN + bin;
    int v = histM[idx];
    histM[idx] = run;
    run += v;
  }
  tiletot[(size_t)ct * NBIN + bin] = run;
}

// ------- tile scan pass 2: in-place prefix over tiles + bin totals ---------
__global__ __launch_bounds__(256) void k_cs2(int* __restrict__ tiletot,
    int* __restrict__ bintot, int NBIN, int NCT)
{
  const int bin = blockIdx.x * 256 + threadIdx.x;
  if (bin >= NBIN) return;
  int run = 0;
  for (int t = 0; t < NCT; ++t) {
    size_t idx = (size_t)t * NBIN + bin;
    int v = tiletot[idx];
    tiletot[idx] = run;
    run += v;
  }
  bintot[bin] = run;
}

// ---------------- exclusive scan (verified, reused) ------------------------
__global__ __launch_bounds__(256) void scan1(const int* __restrict__ deg,
    int* __restrict__ offs, int* __restrict__ bsums, int N)
{
  int i = blockIdx.x * 256 + threadIdx.x;
  int lane = threadIdx.x & 63;
  int w = threadIdx.x >> 6;
  int v = (i < N) ? deg[i] : 0;
  int s = v;
  #pragma unroll
  for (int d = 1; d < 64; d <<= 1) {
    int t = __shfl_up(s, d, 64);
    if (lane >= d) s += t;
  }
  __shared__ int wsum[4];
  if (lane == 63) wsum[w] = s;
  __syncthreads();
  int add = 0;
  if (w > 0) add += wsum[0];
  if (w > 1) add += wsum[1];
  if (w > 2) add += wsum[2];
  if (i < N) offs[i] = s - v + add;                 // block-exclusive
  if (threadIdx.x == 255) bsums[blockIdx.x] = wsum[0] + wsum[1] + wsum[2] + wsum[3];
}

__global__ __launch_bounds__(512) void scan2(int* bsums, int NB)
{
  __shared__ int lds[512];
  int t = threadIdx.x;
  int v = (t < NB) ? bsums[t] : 0;
  lds[t] = v;
  __syncthreads();
  for (int s = 1; s < 512; s <<= 1) {
    int a = (t >= s) ? lds[t - s] : 0;
    __syncthreads();
    lds[t] += a;
    __syncthreads();
  }
  if (t < NB) bsums[t] = lds[t] - v;                // exclusive
}

// -------- fill: score + deterministic binned placement (LDS cursors) -------
__global__ __launch_bounds__(256) void k_fill2(const int* __restrict__ ei,
    const float* __restrict__ et, const int* __restrict__ ctime,
    const float* __restrict__ drate, const float4* __restrict__ u,
    const float4* __restrict__ v, const float* __restrict__ attn_b,
    const int* __restrict__ offsb, const int* __restrict__ bsumsb,
    const int* __restrict__ tiletot, const int* __restrict__ histM,
    int4* __restrict__ csr, int E, int NBIN)
{
  __shared__ int cur[MAXBIN];
  const int cb = blockIdx.x;
  const int ct = cb / CTW;
  for (int i = threadIdx.x; i < NBIN; i += 256)
    cur[i] = offsb[i] + bsumsb[i >> 8] + tiletot[(size_t)ct * NBIN + i]
           + histM[(size_t)cb * NBIN + i];
  __syncthreads();

  const float4 ab = *(const float4*)attn_b;
  const float lam = log1pf(__expf(drate[0]));
  const float ctf = (float)ctime[0];
  const int base = cb * CHUNK + threadIdx.x * 8;

  auto doedge = [&](int s, int d, float tv) {
    const float4 us = u[s];
    const float4 vd = v[d];
    const float w = __expf(-lam * (ctf - tv));
    float4 o; float t;
    t = us.x + vd.x + ab.x; t = (t > 0.f ? t : 0.2f * t) * w; o.x = __expf(t);
    t = us.y + vd.y + ab.y; t = (t > 0.f ? t : 0.2f * t) * w; o.y = __expf(t);
    t = us.z + vd.z + ab.z; t = (t > 0.f ? t : 0.2f * t) * w; o.z = __expf(t);
    t = us.w + vd.w + ab.w; t = (t > 0.f ? t : 0.2f * t) * w; o.w = __expf(t);
    int slot = atomicAdd(&cur[d >> BINSH], 1);
    int4 rec;
    rec.x = s;
    rec.y = (int)pk(o.x, o.y);
    rec.z = (int)pk(o.z, o.w);
    rec.w = d & (BINSZ - 1);
    csr[slot] = rec;
  };

  if (base + 7 < E) {
    int4 s0 = *(const int4*)(ei + base);
    int4 s1 = *(const int4*)(ei + base + 4);
    int4 d0 = *(const int4*)(ei + E + base);
    int4 d1 = *(const int4*)(ei + E + base + 4);
    float4 t0 = *(const float4*)(et + base);
    float4 t1 = *(const float4*)(et + base + 4);
    doedge(s0.x, d0.x, t0.x);
    doedge(s0.y, d0.y, t0.y);
    doedge(s0.z, d0.z, t0.z);
    doedge(s0.w, d0.w, t0.w);
    doedge(s1.x, d1.x, t1.x);
    doedge(s1.y, d1.y, t1.y);
    doedge(s1.z, d1.z, t1.z);
    doedge(s1.w, d1.w, t1.w);
  } else {
    for (int e = base; e < E; ++e) doedge(ei[e], ei[E + e], et[e]);
  }
}

// -------- aggregation: block/bin, LDS-atomic accumulate, 8-deep pipeline ---
__global__ __launch_bounds__(256) void k_aggb(const unsigned short* __restrict__ h16,
    const int4* __restrict__ csr, const int* __restrict__ offsb,
    const int* __restrict__ bsumsb, unsigned short* __restrict__ agg,
    int N, int E, int NBIN)
{
  __shared__ int4  srec[MAXREC];            // 16 KB
  __shared__ float accL[BINSZ][4][64];      // 32 KB  [node][h][c]
  __shared__ float denL[BINSZ][4];          // 512 B

  const int bin = blockIdx.x;
  const int start = offsb[bin] + bsumsb[bin >> 8];
  const int end0  = (bin + 1 < NBIN) ? (offsb[bin + 1] + bsumsb[(bin + 1) >> 8]) : E;
  const int cnt = min(end0 - start, MAXREC);

  float* az = (float*)accL;
  for (int i = threadIdx.x; i < BINSZ * 4 * 64; i += 256) az[i] = 0.f;
  if (threadIdx.x < BINSZ * 4) ((float*)denL)[threadIdx.x] = 0.f;
  for (int i = threadIdx.x; i < cnt; i += 256) srec[i] = csr[start + i];
  __syncthreads();

  const int c  = threadIdx.x & 63;
  const int wv = threadIdx.x >> 6;

  // wave processes edges e = wv + 4*k ; groups of 4 k's, prefetch next group
  const int K  = (cnt > wv) ? ((cnt - wv + 3) >> 2) : 0;
  const int Kf = K & ~3;

  #define EIDX(k) (wv + 4 * (k))
  #define PROC(R, G) { \
    const int nd = R.w; \
    const float e0 = bflo(R.y), e1 = bfhi(R.y), e2 = bflo(R.z), e3 = bfhi(R.z); \
    atomicAdd(&accL[nd][0][c], e0 * (G)); \
    atomicAdd(&accL[nd][1][c], e1 * (G)); \
    atomicAdd(&accL[nd][2][c], e2 * (G)); \
    atomicAdd(&accL[nd][3][c], e3 * (G)); \
    if (c < 4) atomicAdd(&denL[nd][c], (c == 0) ? e0 : ((c == 1) ? e1 : ((c == 2) ? e2 : e3))); \
  }

  int4 rA0, rA1, rA2, rA3;
  float gA0 = 0.f, gA1 = 0.f, gA2 = 0.f, gA3 = 0.f;
  if (Kf) {
    rA0 = srec[EIDX(0)]; rA1 = srec[EIDX(1)];
    rA2 = srec[EIDX(2)]; rA3 = srec[EIDX(3)];
    gA0 = bf2f(h16[(size_t)rA0.x * 64 + c]);
    gA1 = bf2f(h16[(size_t)rA1.x * 64 + c]);
    gA2 = bf2f(h16[(size_t)rA2.x * 64 + c]);
    gA3 = bf2f(h16[(size_t)rA3.x * 64 + c]);
  }
  for (int k = 0; k < Kf; k += 4) {
    int4 rB0, rB1, rB2, rB3;
    float gB0, gB1, gB2, gB3;
    const bool more = (k + 4 < Kf);
    if (more) {
      rB0 = srec[EIDX(k + 4)]; rB1 = srec[EIDX(k + 5)];
      rB2 = srec[EIDX(k + 6)]; rB3 = srec[EIDX(k + 7)];
      gB0 = bf2f(h16[(size_t)rB0.x * 64 + c]);
      gB1 = bf2f(h16[(size_t)rB1.x * 64 + c]);
      gB2 = bf2f(h16[(size_t)rB2.x * 64 + c]);
      gB3 = bf2f(h16[(size_t)rB3.x * 64 + c]);
    }
    PROC(rA0, gA0);
    PROC(rA1, gA1);
    PROC(rA2, gA2);
    PROC(rA3, gA3);
    if (more) {
      rA0 = rB0; rA1 = rB1; rA2 = rB2; rA3 = rB3;
      gA0 = gB0; gA1 = gB1; gA2 = gB2; gA3 = gB3;
    }
  }
  for (int k = Kf; k < K; ++k) {            // tail (<=3 edges per wave)
    int4 r = srec[EIDX(k)];
    float g = bf2f(h16[(size_t)r.x * 64 + c]);
    PROC(r, g);
  }
  __syncthreads();

  // epilogue: agg[n][c*4+h] <- accL[nl][h][c] / den
  for (int nl = wv; nl < BINSZ; nl += 4) {
    const int n = bin * BINSZ + nl;
    if (n >= N) break;
    const float d0 = denL[nl][0] + 1e-8f, d1 = denL[nl][1] + 1e-8f;
    const float d2 = denL[nl][2] + 1e-8f, d3 = denL[nl][3] + 1e-8f;
    uint2 w;
    w.x = pk(accL[nl][0][c] / d0, accL[nl][1][c] / d1);
    w.y = pk(accL[nl][2][c] / d2, accL[nl][3][c] / d3);
    *(uint2*)(agg + (size_t)n * 256 + c * 4) = w;   // coalesced b64
  }
}

// ------- proj GEMM via MFMA + fused residual/LN/ReLU epilogue -------------
__global__ __launch_bounds__(256) void k_projm(const unsigned short* __restrict__ agg,
    const unsigned short* __restrict__ Bf, const float* __restrict__ x,
    const float* __restrict__ Pb,
    const float* __restrict__ lg, const float* __restrict__ lb,
    float* __restrict__ out, int N)
{
  const int lane = threadIdx.x & 63;
  const int wv = threadIdx.x >> 6;
  const int nt = blockIdx.x * 4 + wv;           // 16-node tile index
  if (nt * 16 >= N) return;
  const int col  = lane & 15;
  const int quad = lane >> 4;
  const int base = nt * 16;

  int na = base + col; if (na >= N) na = N - 1;
  const unsigned short* aptr = agg + (size_t)na * 256 + quad * 8;

  f32x4 acc0 = {0.f, 0.f, 0.f, 0.f};
  f32x4 acc1 = {0.f, 0.f, 0.f, 0.f};
  f32x4 acc2 = {0.f, 0.f, 0.f, 0.f};
  f32x4 acc3 = {0.f, 0.f, 0.f, 0.f};

  #pragma unroll
  for (int ks = 0; ks < 8; ++ks) {
    bf16x8 av = *(const bf16x8*)(aptr + ks * 32);
    bf16x8 b0 = *(const bf16x8*)(Bf + ((size_t)(ks * 4 + 0) * 64 + lane) * 8);
    bf16x8 b1 = *(const bf16x8*)(Bf + ((size_t)(ks * 4 + 1) * 64 + lane) * 8);
    bf16x8 b2 = *(const bf16x8*)(Bf + ((size_t)(ks * 4 + 2) * 64 + lane) * 8);
    bf16x8 b3 = *(const bf16x8*)(Bf + ((size_t)(ks * 4 + 3) * 64 + lane) * 8);
    acc0 = __builtin_amdgcn_mfma_f32_16x16x32_bf16(av, b0, acc0, 0, 0, 0);
    acc1 = __builtin_amdgcn_mfma_f32_16x16x32_bf16(av, b1, acc1, 0, 0, 0);
    acc2 = __builtin_amdgcn_mfma_f32_16x16x32_bf16(av, b2, acc2, 0, 0, 0);
    acc3 = __builtin_amdgcn_mfma_f32_16x16x32_bf16(av, b3, acc3, 0, 0, 0);
  }

  const float pb0 = Pb[col], pb1 = Pb[16 + col], pb2 = Pb[32 + col], pb3 = Pb[48 + col];
  float v[4][4];                                 // [cb][reg]
  #pragma unroll
  for (int r = 0; r < 4; ++r) {
    int node = base + quad * 4 + r; if (node >= N) node = N - 1;
    const float* xr = x + (size_t)node * 64;
    v[0][r] = acc0[r] + pb0 + xr[col];
    v[1][r] = acc1[r] + pb1 + xr[16 + col];
    v[2][r] = acc2[r] + pb2 + xr[32 + col];
    v[3][r] = acc3[r] + pb3 + xr[48 + col];
  }

  float mu[4], inv[4];
  #pragma unroll
  for (int r = 0; r < 4; ++r) {
    float s = (v[0][r] + v[1][r]) + (v[2][r] + v[3][r]);
    s += __shfl_xor(s, 1, 64); s += __shfl_xor(s, 2, 64);
    s += __shfl_xor(s, 4, 64); s += __shfl_xor(s, 8, 64);
    mu[r] = s * 0.015625f;
  }
  #pragma unroll
  for (int r = 0; r < 4; ++r) {
    float d0 = v[0][r] - mu[r], d1 = v[1][r] - mu[r];
    float d2 = v[2][r] - mu[r], d3 = v[3][r] - mu[r];
    float s = fmaf(d0, d0, d1 * d1) + fmaf(d2, d2, d3 * d3);
    s += __shfl_xor(s, 1, 64); s += __shfl_xor(s, 2, 64);
    s += __shfl_xor(s, 4, 64); s += __shfl_xor(s, 8, 64);
    inv[r] = rsqrtf(s * 0.015625f + 1e-5f);
  }

  const float lg0 = lg[col], lg1 = lg[16 + col], lg2 = lg[32 + col], lg3 = lg[48 + col];
  const float lb0 = lb[col], lb1 = lb[16 + col], lb2 = lb[32 + col], lb3 = lb[48 + col];
  #pragma unroll
  for (int r = 0; r < 4; ++r) {
    int node = base + quad * 4 + r;
    if (node < N) {
      float* orow = out + (size_t)node * 64;
      orow[col]      = fmaxf(fmaf(lg0 * (v[0][r] - mu[r]), inv[r], lb0), 0.f);
      orow[16 + col] = fmaxf(fmaf(lg1 * (v[1][r] - mu[r]), inv[r], lb1), 0.f);
      orow[32 + col] = fmaxf(fmaf(lg2 * (v[2][r] - mu[r]), inv[r], lb2), 0.f);
      orow[48 + col] = fmaxf(fmaf(lg3 * (v[3][r] - mu[r]), inv[r], lb3), 0.f);
    }
  }
}

// ---------------------------------------------------------------------------
extern "C" void kernel_launch(void* const* d_in, const int* in_sizes, int n_in,
                              void* d_out, int out_size, void* d_ws, size_t ws_size,
                              hipStream_t stream)
{
  const float* x  = (const float*)d_in[0];
  const int*   ei = (const int*)d_in[1];
  const float* et = (const float*)d_in[2];
  const int*   ct = (const int*)d_in[3];
  const float* Ww = (const float*)d_in[4];
  const float* Wb = (const float*)d_in[5];
  const float* aw = (const float*)d_in[6];
  const float* ab = (const float*)d_in[7];
  const float* dr = (const float*)d_in[8];
  const float* Pw = (const float*)d_in[9];
  const float* Pb = (const float*)d_in[10];
  const float* lg = (const float*)d_in[11];
  const float* lb = (const float*)d_in[12];
  float* out = (float*)d_out;

  const int N = in_sizes[0] / 64;
  const int E = in_sizes[2];
  const int NBIN = (N + BINSZ - 1) >> BINSH;
  const int NCH  = (E + CHUNK - 1) / CHUNK;       // histogram/scatter chunks
  const int NCT  = (NCH + CTW - 1) / CTW;         // scan tiles along chunks
  const int NBB  = (NBIN + 255) / 256;            // blocks over bins

  char* ws = (char*)d_ws;
  size_t off = 0;
  auto take = [&](size_t bytes) -> char* {
    char* p = ws + off;
    off = (off + bytes + 255) & ~(size_t)255;
    return p;
  };
  unsigned short* h16 = (unsigned short*)take((size_t)N * 64 * 2);
  int4*   csr    = (int4*)take((size_t)E * 16);
  unsigned short* agg = (unsigned short*)take((size_t)N * 256 * 2);
  float4* u      = (float4*)take((size_t)N * 16);
  float4* v      = (float4*)take((size_t)N * 16);
  unsigned short* Bf = (unsigned short*)take(16384 * 2);
  unsigned short* Ah = (unsigned short*)take(5120 * 2);
  unsigned short* Al = (unsigned short*)take(5120 * 2);
  float*  bc     = (float*)take(80 * 4);
  int*    histM  = (int*)take((size_t)NCH * NBIN * 4);
  int*    tiletot= (int*)take((size_t)NCT * NBIN * 4);
  int*    bintot = (int*)take((size_t)NBIN * 4);
  int*    offsb  = (int*)take((size_t)NBIN * 4);
  int*    bsumsb = (int*)take(512 * 4);

  const int NBn = (N + 255) / 256;

  k_init<<<65 + NCH, 256, 0, stream>>>(Pw, Ww, Wb, aw, ei, Bf, Ah, Al, bc, histM, E, NBIN);
  k_hd<<<NBn, 256, 0, stream>>>(x, Ah, Al, bc, h16, u, v, N);
  k_cs1<<<NCT * NBB, 256, 0, stream>>>(histM, tiletot, NBIN, NCH, NBB);
  k_cs2<<<NBB, 256, 0, stream>>>(tiletot, bintot, NBIN, NCT);
  scan1<<<NBB, 256, 0, stream>>>(bintot, offsb, bsumsb, NBIN);
  scan2<<<1, 512, 0, stream>>>(bsumsb, NBB);
  k_fill2<<<NCH, 256, 0, stream>>>(ei, et, ct, dr, u, v, ab, offsb, bsumsb, tiletot, histM, csr, E, NBIN);
  k_aggb<<<NBIN, 256, 0, stream>>>(h16, csr, offsb, bsumsb, agg, N, E, NBIN);
  const int NT = (N + 15) / 16;
  k_projm<<<(NT + 3) / 4, 256, 0, stream>>>(agg, Bf, x, Pb, lg, lb, out, N);
}

// Round 5
// 269.406 us; speedup vs baseline: 4.8756x; 4.8756x over previous
//
#include <hip/hip_runtime.h>

// ---------------------------------------------------------------------------
// TemporalHeteroConv on MI355X.  N=100000 nodes, E=800000 edges, C=64, H=4.
// r13: r12's fp32 LDS atomicAdd was a CAS-loop disaster (1140us, ~10K cy/edge,
// VALUBusy 4%). Replace agg phase with verified-fast components:
//   k_sortb  : block/bin in-place node-sort of the bin's csr records
//              (register staging + native INT LDS histogram) + per-node CSR
//              offs[N+1] emission.  No fp atomics anywhere.
//   k_agg    : the r6/r9 winner verbatim (wave/node, 4-group/4-prefetch,
//              8 gathers in flight), fed by offs[n]/offs[n+1].
// Rest of pipeline = r12 (passed, fixed scans):
//   k_init   : Pw B-frags + Wt A-frags + per-chunk LDS bin histograms (int).
//   k_hd     : node-only MFMA GEMM h16|u|v.
//   k_cs1/2  : coalesced two-level chunk-prefix over histM.
//   scan1/2  : exclusive scan of bintot -> offsb/bsumsb.
//   k_fill2  : score + binned placement via LDS int cursors, 16B record/edge.
//   k_projm  : MFMA proj GEMM + LN/residual/ReLU epilogue (untouched).
// ---------------------------------------------------------------------------

typedef __attribute__((ext_vector_type(8))) short bf16x8;
typedef __attribute__((ext_vector_type(4))) float f32x4;

#define CHUNK  2048          // edges per histogram/scatter block
#define BINSH  5             // 32 nodes per bin
#define BINSZ  32
#define MAXBIN 3200          // >= ceil(102400/32)
#define MAXREC 1024          // Poisson(256): P(cnt>1024) ~ 0
#define CTW    32            // chunks per scan tile

__device__ __forceinline__ unsigned short f2bf(float f) {
  unsigned int u = __float_as_uint(f);
  u += 0x7FFFu + ((u >> 16) & 1u);          // RNE
  return (unsigned short)(u >> 16);
}
__device__ __forceinline__ float bf2f(unsigned short s) {
  return __uint_as_float(((unsigned int)s) << 16);
}
__device__ __forceinline__ unsigned int pk(float a, float b) {
  return (unsigned int)f2bf(a) | ((unsigned int)f2bf(b) << 16);
}
__device__ __forceinline__ float bflo(int u) {
  return __uint_as_float(((unsigned int)u) << 16);
}
__device__ __forceinline__ float bfhi(int u) {
  return __uint_as_float(((unsigned int)u) & 0xFFFF0000u);
}

// split 8 fp32 into bf16 hi + bf16 lo(residual) fragments
__device__ __forceinline__ void split8(float4 a, float4 b, bf16x8* hi, bf16x8* lo) {
  float f[8] = {a.x, a.y, a.z, a.w, b.x, b.y, b.z, b.w};
  bf16x8 h, l;
  #pragma unroll
  for (int j = 0; j < 8; ++j) {
    unsigned short hs = f2bf(f[j]);
    h[j] = (short)hs;
    l[j] = (short)f2bf(f[j] - bf2f(hs));
  }
  *hi = h; *lo = l;
}

// ------- init: Bf pack (b<64) + Wt A-frags (b==64) + edge histograms -------
__global__ __launch_bounds__(256) void k_init(const float* __restrict__ Pw,
    const float* __restrict__ Ww, const float* __restrict__ Wb,
    const float* __restrict__ aw, const int* __restrict__ ei,
    unsigned short* __restrict__ Bf, unsigned short* __restrict__ Ah,
    unsigned short* __restrict__ Al, float* __restrict__ bc,
    int* __restrict__ histM, int E, int NBIN)
{
  __shared__ int hist[MAXBIN];
  const int b = blockIdx.x;
  if (b < 64) {                      // ---- Pw -> bf16 B-fragment order ----
    int i = b * 256 + threadIdx.x;   // i < 16384
    int j    = i & 7;
    int lane = (i >> 3) & 63;
    int cb   = (i >> 9) & 3;
    int ks   = i >> 11;
    int k    = ks * 32 + (lane >> 4) * 8 + j;
    int colg = cb * 16 + (lane & 15);
    Bf[i] = f2bf(Pw[(size_t)k * 64 + colg]);
    return;
  }
  if (b == 64) {                     // ---- combined Wt(80x64) A-frags ----
    int t = threadIdx.x;
    for (int i = t; i < 5120; i += 256) {
      int j = i & 7, lane = (i >> 3) & 63, ks = (i >> 9) & 1, rb = i >> 10;
      int row = rb * 16 + (lane & 15);
      int k   = ks * 32 + (lane >> 4) * 8 + j;
      float w = 0.f;
      if (row < 64) {
        w = Ww[(size_t)k * 64 + row];
      } else if (row < 72) {
        int jj = row - 64;
        const float* ac = (jj < 4) ? (aw + jj) : (aw + 256 + (jj - 4));
        float s = 0.f;
        for (int c = 0; c < 64; ++c) s = fmaf(Ww[(size_t)k * 64 + c], ac[c * 4], s);
        w = s;
      }
      unsigned short hh = f2bf(w);
      Ah[i] = hh;
      Al[i] = f2bf(w - bf2f(hh));
    }
    if (t < 80) {
      float bb = 0.f;
      if (t < 64) {
        bb = Wb[t];
      } else if (t < 72) {
        int jj = t - 64;
        const float* ac = (jj < 4) ? (aw + jj) : (aw + 256 + (jj - 4));
        float s = 0.f;
        for (int c = 0; c < 64; ++c) s = fmaf(Wb[c], ac[c * 4], s);
        bb = s;
      }
      bc[t] = bb;
    }
    return;
  }
  // ---- per-chunk bin histogram (native INT LDS atomics) ----
  const int cb = b - 65;
  for (int i = threadIdx.x; i < NBIN; i += 256) hist[i] = 0;
  __syncthreads();
  const int base = cb * CHUNK + threadIdx.x * 8;
  const int* dptr = ei + E;
  if (base + 7 < E) {
    int4 d0 = *(const int4*)(dptr + base);
    int4 d1 = *(const int4*)(dptr + base + 4);
    atomicAdd(&hist[d0.x >> BINSH], 1);
    atomicAdd(&hist[d0.y >> BINSH], 1);
    atomicAdd(&hist[d0.z >> BINSH], 1);
    atomicAdd(&hist[d0.w >> BINSH], 1);
    atomicAdd(&hist[d1.x >> BINSH], 1);
    atomicAdd(&hist[d1.y >> BINSH], 1);
    atomicAdd(&hist[d1.z >> BINSH], 1);
    atomicAdd(&hist[d1.w >> BINSH], 1);
  } else {
    for (int e = base; e < E; ++e) atomicAdd(&hist[dptr[e] >> BINSH], 1);
  }
  __syncthreads();
  for (int i = threadIdx.x; i < NBIN; i += 256)
    histM[(size_t)cb * NBIN + i] = hist[i];
}

// ------- node-only MFMA GEMM h|u|v (r10 path, verified) --------------------
#define RBSTEP(ACC, RB) { \
  bf16x8 fh0 = *(const bf16x8*)(Ah + ((RB * 2 + 0) * 64 + lane) * 8); \
  bf16x8 fl0 = *(const bf16x8*)(Al + ((RB * 2 + 0) * 64 + lane) * 8); \
  bf16x8 fh1 = *(const bf16x8*)(Ah + ((RB * 2 + 1) * 64 + lane) * 8); \
  bf16x8 fl1 = *(const bf16x8*)(Al + ((RB * 2 + 1) * 64 + lane) * 8); \
  ACC = __builtin_amdgcn_mfma_f32_16x16x32_bf16(fh0, bh0, ACC, 0, 0, 0); \
  ACC = __builtin_amdgcn_mfma_f32_16x16x32_bf16(fl0, bh0, ACC, 0, 0, 0); \
  ACC = __builtin_amdgcn_mfma_f32_16x16x32_bf16(fh0, bl0, ACC, 0, 0, 0); \
  ACC = __builtin_amdgcn_mfma_f32_16x16x32_bf16(fh1, bh1, ACC, 0, 0, 0); \
  ACC = __builtin_amdgcn_mfma_f32_16x16x32_bf16(fl1, bh1, ACC, 0, 0, 0); \
  ACC = __builtin_amdgcn_mfma_f32_16x16x32_bf16(fh1, bl1, ACC, 0, 0, 0); \
}

__global__ __launch_bounds__(256, 4) void k_hd(const float* __restrict__ x,
    const unsigned short* __restrict__ Ah, const unsigned short* __restrict__ Al,
    const float* __restrict__ bc, unsigned short* __restrict__ h16,
    float4* __restrict__ u, float4* __restrict__ v, int N)
{
  const int lane = threadIdx.x & 63;
  const int wv   = threadIdx.x >> 6;
  const int col  = lane & 15;
  const int quad = lane >> 4;

  const float4 bc0 = *(const float4*)(bc +  0 + quad * 4);
  const float4 bc1 = *(const float4*)(bc + 16 + quad * 4);
  const float4 bc2 = *(const float4*)(bc + 32 + quad * 4);
  const float4 bc3 = *(const float4*)(bc + 48 + quad * 4);
  const float4 bc4 = *(const float4*)(bc + 64 + quad * 4);

  const int base0 = blockIdx.x * 256 + wv * 64;
  for (int st = 0; st < 4; ++st) {
    const int node = base0 + st * 16 + col;
    const bool val = (node < N);
    const int nc = val ? node : N - 1;
    const float* xr = x + (size_t)nc * 64 + quad * 8;
    float4 x0 = *(const float4*)(xr);
    float4 x1 = *(const float4*)(xr + 4);
    float4 x2 = *(const float4*)(xr + 32);
    float4 x3 = *(const float4*)(xr + 36);
    bf16x8 bh0, bl0, bh1, bl1;
    split8(x0, x1, &bh0, &bl0);
    split8(x2, x3, &bh1, &bl1);

    f32x4 a0 = {0.f, 0.f, 0.f, 0.f};
    f32x4 a1 = {0.f, 0.f, 0.f, 0.f};
    f32x4 a2 = {0.f, 0.f, 0.f, 0.f};
    f32x4 a3 = {0.f, 0.f, 0.f, 0.f};
    f32x4 a4 = {0.f, 0.f, 0.f, 0.f};
    RBSTEP(a0, 0);
    RBSTEP(a1, 1);
    RBSTEP(a2, 2);
    RBSTEP(a3, 3);
    RBSTEP(a4, 4);

    if (val) {
      unsigned short* hr = h16 + (size_t)node * 64 + quad * 4;
      uint2 w0, w1, w2, w3;
      w0.x = pk(a0[0] + bc0.x, a0[1] + bc0.y);
      w0.y = pk(a0[2] + bc0.z, a0[3] + bc0.w);
      w1.x = pk(a1[0] + bc1.x, a1[1] + bc1.y);
      w1.y = pk(a1[2] + bc1.z, a1[3] + bc1.w);
      w2.x = pk(a2[0] + bc2.x, a2[1] + bc2.y);
      w2.y = pk(a2[2] + bc2.z, a2[3] + bc2.w);
      w3.x = pk(a3[0] + bc3.x, a3[1] + bc3.y);
      w3.y = pk(a3[2] + bc3.z, a3[3] + bc3.w);
      *(uint2*)(hr)      = w0;
      *(uint2*)(hr + 16) = w1;
      *(uint2*)(hr + 32) = w2;
      *(uint2*)(hr + 48) = w3;
      if (quad == 0)
        u[node] = make_float4(a4[0] + bc4.x, a4[1] + bc4.y, a4[2] + bc4.z, a4[3] + bc4.w);
      else if (quad == 1)
        v[node] = make_float4(a4[0] + bc4.x, a4[1] + bc4.y, a4[2] + bc4.z, a4[3] + bc4.w);
    }
  }
}

// ------- tile scan pass 1: in-place prefix over CTW chunks, coalesced ------
__global__ __launch_bounds__(256) void k_cs1(int* __restrict__ histM,
    int* __restrict__ tiletot, int NBIN, int NCH, int NBB)
{
  const int ct = blockIdx.x / NBB;
  const int bb = blockIdx.x - ct * NBB;
  const int bin = bb * 256 + threadIdx.x;
  if (bin >= NBIN) return;
  const int b0 = ct * CTW;
  const int b1 = min(b0 + CTW, NCH);
  int run = 0;
  for (int b = b0; b < b1; ++b) {
    size_t idx = (size_t)b * NBIN + bin;
    int v = histM[idx];
    histM[idx] = run;
    run += v;
  }
  tiletot[(size_t)ct * NBIN + bin] = run;
}

// ------- tile scan pass 2: in-place prefix over tiles + bin totals ---------
__global__ __launch_bounds__(256) void k_cs2(int* __restrict__ tiletot,
    int* __restrict__ bintot, int NBIN, int NCT)
{
  const int bin = blockIdx.x * 256 + threadIdx.x;
  if (bin >= NBIN) return;
  int run = 0;
  for (int t = 0; t < NCT; ++t) {
    size_t idx = (size_t)t * NBIN + bin;
    int v = tiletot[idx];
    tiletot[idx] = run;
    run += v;
  }
  bintot[bin] = run;
}

// ---------------- exclusive scan (verified, reused) ------------------------
__global__ __launch_bounds__(256) void scan1(const int* __restrict__ deg,
    int* __restrict__ offs, int* __restrict__ bsums, int N)
{
  int i = blockIdx.x * 256 + threadIdx.x;
  int lane = threadIdx.x & 63;
  int w = threadIdx.x >> 6;
  int v = (i < N) ? deg[i] : 0;
  int s = v;
  #pragma unroll
  for (int d = 1; d < 64; d <<= 1) {
    int t = __shfl_up(s, d, 64);
    if (lane >= d) s += t;
  }
  __shared__ int wsum[4];
  if (lane == 63) wsum[w] = s;
  __syncthreads();
  int add = 0;
  if (w > 0) add += wsum[0];
  if (w > 1) add += wsum[1];
  if (w > 2) add += wsum[2];
  if (i < N) offs[i] = s - v + add;                 // block-exclusive
  if (threadIdx.x == 255) bsums[blockIdx.x] = wsum[0] + wsum[1] + wsum[2] + wsum[3];
}

__global__ __launch_bounds__(512) void scan2(int* bsums, int NB)
{
  __shared__ int lds[512];
  int t = threadIdx.x;
  int v = (t < NB) ? bsums[t] : 0;
  lds[t] = v;
  __syncthreads();
  for (int s = 1; s < 512; s <<= 1) {
    int a = (t >= s) ? lds[t - s] : 0;
    __syncthreads();
    lds[t] += a;
    __syncthreads();
  }
  if (t < NB) bsums[t] = lds[t] - v;                // exclusive
}

// -------- fill: score + deterministic binned placement (LDS int cursors) ---
__global__ __launch_bounds__(256) void k_fill2(const int* __restrict__ ei,
    const float* __restrict__ et, const int* __restrict__ ctime,
    const float* __restrict__ drate, const float4* __restrict__ u,
    const float4* __restrict__ v, const float* __restrict__ attn_b,
    const int* __restrict__ offsb, const int* __restrict__ bsumsb,
    const int* __restrict__ tiletot, const int* __restrict__ histM,
    int4* __restrict__ csr, int E, int NBIN)
{
  __shared__ int cur[MAXBIN];
  const int cb = blockIdx.x;
  const int ct = cb / CTW;
  for (int i = threadIdx.x; i < NBIN; i += 256)
    cur[i] = offsb[i] + bsumsb[i >> 8] + tiletot[(size_t)ct * NBIN + i]
           + histM[(size_t)cb * NBIN + i];
  __syncthreads();

  const float4 ab = *(const float4*)attn_b;
  const float lam = log1pf(__expf(drate[0]));
  const float ctf = (float)ctime[0];
  const int base = cb * CHUNK + threadIdx.x * 8;

  auto doedge = [&](int s, int d, float tv) {
    const float4 us = u[s];
    const float4 vd = v[d];
    const float w = __expf(-lam * (ctf - tv));
    float4 o; float t;
    t = us.x + vd.x + ab.x; t = (t > 0.f ? t : 0.2f * t) * w; o.x = __expf(t);
    t = us.y + vd.y + ab.y; t = (t > 0.f ? t : 0.2f * t) * w; o.y = __expf(t);
    t = us.z + vd.z + ab.z; t = (t > 0.f ? t : 0.2f * t) * w; o.z = __expf(t);
    t = us.w + vd.w + ab.w; t = (t > 0.f ? t : 0.2f * t) * w; o.w = __expf(t);
    int slot = atomicAdd(&cur[d >> BINSH], 1);      // INT LDS atomic (native)
    int4 rec;
    rec.x = s;
    rec.y = (int)pk(o.x, o.y);
    rec.z = (int)pk(o.z, o.w);
    rec.w = d & (BINSZ - 1);
    csr[slot] = rec;
  };

  if (base + 7 < E) {
    int4 s0 = *(const int4*)(ei + base);
    int4 s1 = *(const int4*)(ei + base + 4);
    int4 d0 = *(const int4*)(ei + E + base);
    int4 d1 = *(const int4*)(ei + E + base + 4);
    float4 t0 = *(const float4*)(et + base);
    float4 t1 = *(const float4*)(et + base + 4);
    doedge(s0.x, d0.x, t0.x);
    doedge(s0.y, d0.y, t0.y);
    doedge(s0.z, d0.z, t0.z);
    doedge(s0.w, d0.w, t0.w);
    doedge(s1.x, d1.x, t1.x);
    doedge(s1.y, d1.y, t1.y);
    doedge(s1.z, d1.z, t1.z);
    doedge(s1.w, d1.w, t1.w);
  } else {
    for (int e = base; e < E; ++e) doedge(ei[e], ei[E + e], et[e]);
  }
}

// -------- in-place node-sort within each bin + per-node CSR offsets --------
__global__ __launch_bounds__(256) void k_sortb(const int* __restrict__ offsb,
    const int* __restrict__ bsumsb, int4* __restrict__ csr,
    int* __restrict__ offs, int N, int E, int NBIN)
{
  __shared__ int hcnt[BINSZ];
  __shared__ int nbase[BINSZ + 1];
  __shared__ int cur[BINSZ];

  const int bin = blockIdx.x;
  const int start = offsb[bin] + bsumsb[bin >> 8];
  const int end0  = (bin + 1 < NBIN) ? (offsb[bin + 1] + bsumsb[(bin + 1) >> 8]) : E;
  const int cnt = min(end0 - start, MAXREC);

  if (threadIdx.x < BINSZ) hcnt[threadIdx.x] = 0;
  __syncthreads();

  // read phase: stage up to 4 records per thread into registers
  int4 r0 = {0,0,0,0}, r1 = {0,0,0,0}, r2 = {0,0,0,0}, r3 = {0,0,0,0};
  const int i0 = threadIdx.x, i1 = i0 + 256, i2 = i0 + 512, i3 = i0 + 768;
  const bool b0 = i0 < cnt, b1 = i1 < cnt, b2 = i2 < cnt, b3 = i3 < cnt;
  if (b0) { r0 = csr[start + i0]; atomicAdd(&hcnt[r0.w], 1); }
  if (b1) { r1 = csr[start + i1]; atomicAdd(&hcnt[r1.w], 1); }
  if (b2) { r2 = csr[start + i2]; atomicAdd(&hcnt[r2.w], 1); }
  if (b3) { r3 = csr[start + i3]; atomicAdd(&hcnt[r3.w], 1); }
  __syncthreads();                        // all reads done before any write

  if (threadIdx.x == 0) {
    int run = 0;
    #pragma unroll
    for (int i = 0; i < BINSZ; ++i) { nbase[i] = run; cur[i] = run; run += hcnt[i]; }
    nbase[BINSZ] = run;
  }
  __syncthreads();

  if (threadIdx.x < BINSZ) {
    int n = bin * BINSZ + threadIdx.x;
    if (n < N) offs[n] = start + nbase[threadIdx.x];
  }
  if (bin == 0 && threadIdx.x == 255) offs[N] = E;

  // write phase: scatter back sorted (disjoint region per block)
  if (b0) csr[start + atomicAdd(&cur[r0.w], 1)] = r0;
  if (b1) csr[start + atomicAdd(&cur[r1.w], 1)] = r1;
  if (b2) csr[start + atomicAdd(&cur[r2.w], 1)] = r2;
  if (b3) csr[start + atomicAdd(&cur[r3.w], 1)] = r3;
}

// -------- aggregation: wave/node, pipelined 4-edge groups (r6 winner) ------
__global__ __launch_bounds__(256) void k_agg(const unsigned short* __restrict__ h16,
    const int4* __restrict__ csr, const int* __restrict__ offs,
    unsigned short* __restrict__ agg, int N)
{
  const int c = threadIdx.x & 63;
  const int wid = blockIdx.x * 4 + (threadIdx.x >> 6);
  const int wstride = gridDim.x * 4;

  for (int n0 = wid; n0 < N; n0 += wstride) {
    const int n = __builtin_amdgcn_readfirstlane(n0);
    const int p0 = offs[n];
    const int p1 = offs[n + 1];
    const int nf = (p1 - p0) & ~3;                  // full-group edge count

    float acc0 = 0.f, acc1 = 0.f, acc2 = 0.f, acc3 = 0.f;
    float den0 = 0.f, den1 = 0.f, den2 = 0.f, den3 = 0.f;

    int4 rA0, rA1, rA2, rA3;                        // records: uniform s_loads
    float gA0 = 0.f, gA1 = 0.f, gA2 = 0.f, gA3 = 0.f;
    if (nf) {
      rA0 = csr[p0];     rA1 = csr[p0 + 1];
      rA2 = csr[p0 + 2]; rA3 = csr[p0 + 3];
      gA0 = bf2f(h16[(size_t)rA0.x * 64 + c]);
      gA1 = bf2f(h16[(size_t)rA1.x * 64 + c]);
      gA2 = bf2f(h16[(size_t)rA2.x * 64 + c]);
      gA3 = bf2f(h16[(size_t)rA3.x * 64 + c]);
    }
    for (int p = p0; p < p0 + nf; p += 4) {
      int4 rB0, rB1, rB2, rB3;
      float gB0, gB1, gB2, gB3;
      const bool more = (p + 4 < p0 + nf);
      if (more) {                                   // prefetch next group
        rB0 = csr[p + 4]; rB1 = csr[p + 5];
        rB2 = csr[p + 6]; rB3 = csr[p + 7];
        gB0 = bf2f(h16[(size_t)rB0.x * 64 + c]);
        gB1 = bf2f(h16[(size_t)rB1.x * 64 + c]);
        gB2 = bf2f(h16[(size_t)rB2.x * 64 + c]);
        gB3 = bf2f(h16[(size_t)rB3.x * 64 + c]);
      }
      // scalar unpack of bf16 es (wave-uniform)
      float e00 = bflo(rA0.y), e01 = bfhi(rA0.y), e02 = bflo(rA0.z), e03 = bfhi(rA0.z);
      float e10 = bflo(rA1.y), e11 = bfhi(rA1.y), e12 = bflo(rA1.z), e13 = bfhi(rA1.z);
      float e20 = bflo(rA2.y), e21 = bfhi(rA2.y), e22 = bflo(rA2.z), e23 = bfhi(rA2.z);
      float e30 = bflo(rA3.y), e31 = bfhi(rA3.y), e32 = bflo(rA3.z), e33 = bfhi(rA3.z);
      den0 += (e00 + e10) + (e20 + e30);
      den1 += (e01 + e11) + (e21 + e31);
      den2 += (e02 + e12) + (e22 + e32);
      den3 += (e03 + e13) + (e23 + e33);
      acc0 = fmaf(e00, gA0, fmaf(e10, gA1, fmaf(e20, gA2, fmaf(e30, gA3, acc0))));
      acc1 = fmaf(e01, gA0, fmaf(e11, gA1, fmaf(e21, gA2, fmaf(e31, gA3, acc1))));
      acc2 = fmaf(e02, gA0, fmaf(e12, gA1, fmaf(e22, gA2, fmaf(e32, gA3, acc2))));
      acc3 = fmaf(e03, gA0, fmaf(e13, gA1, fmaf(e23, gA2, fmaf(e33, gA3, acc3))));
      if (more) {
        rA0 = rB0; rA1 = rB1; rA2 = rB2; rA3 = rB3;
        gA0 = gB0; gA1 = gB1; gA2 = gB2; gA3 = gB3;
      }
    }
    for (int p = p0 + nf; p < p1; ++p) {            // tail (<=3, wave-uniform)
      int4 r = csr[p];
      float g = bf2f(h16[(size_t)r.x * 64 + c]);
      float e0 = bflo(r.y), e1 = bfhi(r.y), e2 = bflo(r.z), e3 = bfhi(r.z);
      den0 += e0; den1 += e1; den2 += e2; den3 += e3;
      acc0 = fmaf(e0, g, acc0);
      acc1 = fmaf(e1, g, acc1);
      acc2 = fmaf(e2, g, acc2);
      acc3 = fmaf(e3, g, acc3);
    }
    uint2 w;
    w.x = pk(acc0 / (den0 + 1e-8f), acc1 / (den1 + 1e-8f));
    w.y = pk(acc2 / (den2 + 1e-8f), acc3 / (den3 + 1e-8f));
    *(uint2*)(agg + (size_t)n * 256 + c * 4) = w;   // coalesced b64
  }
}

// ------- proj GEMM via MFMA + fused residual/LN/ReLU epilogue -------------
__global__ __launch_bounds__(256) void k_projm(const unsigned short* __restrict__ agg,
    const unsigned short* __restrict__ Bf, const float* __restrict__ x,
    const float* __restrict__ Pb,
    const float* __restrict__ lg, const float* __restrict__ lb,
    float* __restrict__ out, int N)
{
  const int lane = threadIdx.x & 63;
  const int wv = threadIdx.x >> 6;
  const int nt = blockIdx.x * 4 + wv;           // 16-node tile index
  if (nt * 16 >= N) return;
  const int col  = lane & 15;
  const int quad = lane >> 4;
  const int base = nt * 16;

  int na = base + col; if (na >= N) na = N - 1;
  const unsigned short* aptr = agg + (size_t)na * 256 + quad * 8;

  f32x4 acc0 = {0.f, 0.f, 0.f, 0.f};
  f32x4 acc1 = {0.f, 0.f, 0.f, 0.f};
  f32x4 acc2 = {0.f, 0.f, 0.f, 0.f};
  f32x4 acc3 = {0.f, 0.f, 0.f, 0.f};

  #pragma unroll
  for (int ks = 0; ks < 8; ++ks) {
    bf16x8 av = *(const bf16x8*)(aptr + ks * 32);
    bf16x8 b0 = *(const bf16x8*)(Bf + ((size_t)(ks * 4 + 0) * 64 + lane) * 8);
    bf16x8 b1 = *(const bf16x8*)(Bf + ((size_t)(ks * 4 + 1) * 64 + lane) * 8);
    bf16x8 b2 = *(const bf16x8*)(Bf + ((size_t)(ks * 4 + 2) * 64 + lane) * 8);
    bf16x8 b3 = *(const bf16x8*)(Bf + ((size_t)(ks * 4 + 3) * 64 + lane) * 8);
    acc0 = __builtin_amdgcn_mfma_f32_16x16x32_bf16(av, b0, acc0, 0, 0, 0);
    acc1 = __builtin_amdgcn_mfma_f32_16x16x32_bf16(av, b1, acc1, 0, 0, 0);
    acc2 = __builtin_amdgcn_mfma_f32_16x16x32_bf16(av, b2, acc2, 0, 0, 0);
    acc3 = __builtin_amdgcn_mfma_f32_16x16x32_bf16(av, b3, acc3, 0, 0, 0);
  }

  const float pb0 = Pb[col], pb1 = Pb[16 + col], pb2 = Pb[32 + col], pb3 = Pb[48 + col];
  float v[4][4];                                 // [cb][reg]
  #pragma unroll
  for (int r = 0; r < 4; ++r) {
    int node = base + quad * 4 + r; if (node >= N) node = N - 1;
    const float* xr = x + (size_t)node * 64;
    v[0][r] = acc0[r] + pb0 + xr[col];
    v[1][r] = acc1[r] + pb1 + xr[16 + col];
    v[2][r] = acc2[r] + pb2 + xr[32 + col];
    v[3][r] = acc3[r] + pb3 + xr[48 + col];
  }

  float mu[4], inv[4];
  #pragma unroll
  for (int r = 0; r < 4; ++r) {
    float s = (v[0][r] + v[1][r]) + (v[2][r] + v[3][r]);
    s += __shfl_xor(s, 1, 64); s += __shfl_xor(s, 2, 64);
    s += __shfl_xor(s, 4, 64); s += __shfl_xor(s, 8, 64);
    mu[r] = s * 0.015625f;
  }
  #pragma unroll
  for (int r = 0; r < 4; ++r) {
    float d0 = v[0][r] - mu[r], d1 = v[1][r] - mu[r];
    float d2 = v[2][r] - mu[r], d3 = v[3][r] - mu[r];
    float s = fmaf(d0, d0, d1 * d1) + fmaf(d2, d2, d3 * d3);
    s += __shfl_xor(s, 1, 64); s += __shfl_xor(s, 2, 64);
    s += __shfl_xor(s, 4, 64); s += __shfl_xor(s, 8, 64);
    inv[r] = rsqrtf(s * 0.015625f + 1e-5f);
  }

  const float lg0 = lg[col], lg1 = lg[16 + col], lg2 = lg[32 + col], lg3 = lg[48 + col];
  const float lb0 = lb[col], lb1 = lb[16 + col], lb2 = lb[32 + col], lb3 = lb[48 + col];
  #pragma unroll
  for (int r = 0; r < 4; ++r) {
    int node = base + quad * 4 + r;
    if (node < N) {
      float* orow = out + (size_t)node * 64;
      orow[col]      = fmaxf(fmaf(lg0 * (v[0][r] - mu[r]), inv[r], lb0), 0.f);
      orow[16 + col] = fmaxf(fmaf(lg1 * (v[1][r] - mu[r]), inv[r], lb1), 0.f);
      orow[32 + col] = fmaxf(fmaf(lg2 * (v[2][r] - mu[r]), inv[r], lb2), 0.f);
      orow[48 + col] = fmaxf(fmaf(lg3 * (v[3][r] - mu[r]), inv[r], lb3), 0.f);
    }
  }
}

// ---------------------------------------------------------------------------
extern "C" void kernel_launch(void* const* d_in, const int* in_sizes, int n_in,
                              void* d_out, int out_size, void* d_ws, size_t ws_size,
                              hipStream_t stream)
{
  const float* x  = (const float*)d_in[0];
  const int*   ei = (const int*)d_in[1];
  const float* et = (const float*)d_in[2];
  const int*   ct = (const int*)d_in[3];
  const float* Ww = (const float*)d_in[4];
  const float* Wb = (const float*)d_in[5];
  const float* aw = (const float*)d_in[6];
  const float* ab = (const float*)d_in[7];
  const float* dr = (const float*)d_in[8];
  const float* Pw = (const float*)d_in[9];
  const float* Pb = (const float*)d_in[10];
  const float* lg = (const float*)d_in[11];
  const float* lb = (const float*)d_in[12];
  float* out = (float*)d_out;

  const int N = in_sizes[0] / 64;
  const int E = in_sizes[2];
  const int NBIN = (N + BINSZ - 1) >> BINSH;
  const int NCH  = (E + CHUNK - 1) / CHUNK;       // histogram/scatter chunks
  const int NCT  = (NCH + CTW - 1) / CTW;         // scan tiles along chunks
  const int NBB  = (NBIN + 255) / 256;            // blocks over bins

  char* ws = (char*)d_ws;
  size_t off = 0;
  auto take = [&](size_t bytes) -> char* {
    char* p = ws + off;
    off = (off + bytes + 255) & ~(size_t)255;
    return p;
  };
  unsigned short* h16 = (unsigned short*)take((size_t)N * 64 * 2);
  int4*   csr    = (int4*)take((size_t)E * 16);
  unsigned short* agg = (unsigned short*)take((size_t)N * 256 * 2);
  float4* u      = (float4*)take((size_t)N * 16);
  float4* v      = (float4*)take((size_t)N * 16);
  unsigned short* Bf = (unsigned short*)take(16384 * 2);
  unsigned short* Ah = (unsigned short*)take(5120 * 2);
  unsigned short* Al = (unsigned short*)take(5120 * 2);
  float*  bc     = (float*)take(80 * 4);
  int*    histM  = (int*)take((size_t)NCH * NBIN * 4);
  int*    tiletot= (int*)take((size_t)NCT * NBIN * 4);
  int*    bintot = (int*)take((size_t)NBIN * 4);
  int*    offsb  = (int*)take((size_t)NBIN * 4);
  int*    bsumsb = (int*)take(512 * 4);
  int*    offs   = (int*)take(((size_t)N + 1) * 4);

  const int NBn = (N + 255) / 256;

  k_init<<<65 + NCH, 256, 0, stream>>>(Pw, Ww, Wb, aw, ei, Bf, Ah, Al, bc, histM, E, NBIN);
  k_hd<<<NBn, 256, 0, stream>>>(x, Ah, Al, bc, h16, u, v, N);
  k_cs1<<<NCT * NBB, 256, 0, stream>>>(histM, tiletot, NBIN, NCH, NBB);
  k_cs2<<<NBB, 256, 0, stream>>>(tiletot, bintot, NBIN, NCT);
  scan1<<<NBB, 256, 0, stream>>>(bintot, offsb, bsumsb, NBIN);
  scan2<<<1, 512, 0, stream>>>(bsumsb, NBB);
  k_fill2<<<NCH, 256, 0, stream>>>(ei, et, ct, dr, u, v, ab, offsb, bsumsb, tiletot, histM, csr, E, NBIN);
  k_sortb<<<NBIN, 256, 0, stream>>>(offsb, bsumsb, csr, offs, N, E, NBIN);
  k_agg<<<2048, 256, 0, stream>>>(h16, csr, offs, agg, N);
  const int NT = (N + 15) / 16;
  k_projm<<<(NT + 3) / 4, 256, 0, stream>>>(agg, Bf, x, Pb, lg, lb, out, N);
}

// Round 8
// 269.180 us; speedup vs baseline: 4.8797x; 1.0008x over previous
//
#include <hip/hip_runtime.h>

// ---------------------------------------------------------------------------
// TemporalHeteroConv on MI355X.  N=100000 nodes, E=800000 edges, C=64, H=4.
// r16: r13 (verified-passing, 269us) restructured from 11 -> 7 launches.
// Launch-gap analysis: r13 kernel work ~150us vs 269us wall => ~10-12us per
// dispatch overhead.  Changes (all compute arithmetic IDENTICAL to r13):
//   k_inith  : k_init + k_hd fused by block role (r10's proven pattern).
//              Node blocks build Wt fragments in-block into LDS (same code
//              as k_init's block 64 => bit-identical h16/u/v).
//   k_binoff : ONE kernel (1 block) replaces k_cs2+scan1+scan2: column
//              prefix of tiletot in place + block scan -> binbase[NBIN+1].
//   k_cs1    : verbatim.   k_fill2/k_sortb: cursor math uses binbase.
//   k_agg    : verbatim r6 winner.   k_projm: verbatim.
// The agg+projm fusion (r14/r15) is ABANDONED: failed twice (~0.31 absmax,
// survives LDS fence, cause not identified).
// ---------------------------------------------------------------------------

typedef __attribute__((ext_vector_type(8))) short bf16x8;
typedef __attribute__((ext_vector_type(4))) float f32x4;

#define CHUNK  2048          // edges per histogram/scatter block
#define BINSH  5             // 32 nodes per bin
#define BINSZ  32
#define MAXBIN 3200          // >= ceil(102400/32)
#define MAXREC 1024          // Poisson(256): P(cnt>1024) ~ 0
#define CTW    32            // chunks per scan tile
#define MAXCT  16            // >= ceil(NCH/CTW) for E<=1M

__device__ __forceinline__ unsigned short f2bf(float f) {
  unsigned int u = __float_as_uint(f);
  u += 0x7FFFu + ((u >> 16) & 1u);          // RNE
  return (unsigned short)(u >> 16);
}
__device__ __forceinline__ float bf2f(unsigned short s) {
  return __uint_as_float(((unsigned int)s) << 16);
}
__device__ __forceinline__ unsigned int pk(float a, float b) {
  return (unsigned int)f2bf(a) | ((unsigned int)f2bf(b) << 16);
}
__device__ __forceinline__ float bflo(int u) {
  return __uint_as_float(((unsigned int)u) << 16);
}
__device__ __forceinline__ float bfhi(int u) {
  return __uint_as_float(((unsigned int)u) & 0xFFFF0000u);
}

// split 8 fp32 into bf16 hi + bf16 lo(residual) fragments
__device__ __forceinline__ void split8(float4 a, float4 b, bf16x8* hi, bf16x8* lo) {
  float f[8] = {a.x, a.y, a.z, a.w, b.x, b.y, b.z, b.w};
  bf16x8 h, l;
  #pragma unroll
  for (int j = 0; j < 8; ++j) {
    unsigned short hs = f2bf(f[j]);
    h[j] = (short)hs;
    l[j] = (short)f2bf(f[j] - bf2f(hs));
  }
  *hi = h; *lo = l;
}

// ------- fused init: Bf pack | node MFMA GEMM (LDS Wt) | edge histograms ---
#define RBSTEP(ACC, RB) { \
  bf16x8 fh0 = *(const bf16x8*)(AhL + ((RB * 2 + 0) * 64 + lane) * 8); \
  bf16x8 fl0 = *(const bf16x8*)(AlL + ((RB * 2 + 0) * 64 + lane) * 8); \
  bf16x8 fh1 = *(const bf16x8*)(AhL + ((RB * 2 + 1) * 64 + lane) * 8); \
  bf16x8 fl1 = *(const bf16x8*)(AlL + ((RB * 2 + 1) * 64 + lane) * 8); \
  ACC = __builtin_amdgcn_mfma_f32_16x16x32_bf16(fh0, bh0, ACC, 0, 0, 0); \
  ACC = __builtin_amdgcn_mfma_f32_16x16x32_bf16(fl0, bh0, ACC, 0, 0, 0); \
  ACC = __builtin_amdgcn_mfma_f32_16x16x32_bf16(fh0, bl0, ACC, 0, 0, 0); \
  ACC = __builtin_amdgcn_mfma_f32_16x16x32_bf16(fh1, bh1, ACC, 0, 0, 0); \
  ACC = __builtin_amdgcn_mfma_f32_16x16x32_bf16(fl1, bh1, ACC, 0, 0, 0); \
  ACC = __builtin_amdgcn_mfma_f32_16x16x32_bf16(fh1, bl1, ACC, 0, 0, 0); \
}

__global__ __launch_bounds__(256) void k_inith(const float* __restrict__ Pw,
    const float* __restrict__ Ww, const float* __restrict__ Wb,
    const float* __restrict__ aw, const int* __restrict__ ei,
    const float* __restrict__ x, unsigned short* __restrict__ Bf,
    unsigned short* __restrict__ h16, float4* __restrict__ u,
    float4* __restrict__ v, int* __restrict__ histM,
    int N, int E, int NBn, int NBIN)
{
  __shared__ int hist[MAXBIN];
  __shared__ unsigned short AhL[5120];
  __shared__ unsigned short AlL[5120];
  __shared__ float bcL[80];
  const int b = blockIdx.x;
  const int t = threadIdx.x;

  if (b < 64) {                      // ---- Pw -> bf16 B-fragment order ----
    int i = b * 256 + t;             // i < 16384
    int j    = i & 7;
    int lane = (i >> 3) & 63;
    int cb   = (i >> 9) & 3;
    int ks   = i >> 11;
    int k    = ks * 32 + (lane >> 4) * 8 + j;
    int colg = cb * 16 + (lane & 15);
    Bf[i] = f2bf(Pw[(size_t)k * 64 + colg]);
    return;
  }

  if (b < 64 + NBn) {                // ---- node blocks: MFMA GEMM h|u|v ----
    // build combined Wt(80x64) hi/lo fragments in LDS (same math as r13's
    // k_init block 64 => bit-identical results)
    for (int i = t; i < 5120; i += 256) {
      int j = i & 7, lane = (i >> 3) & 63, ks = (i >> 9) & 1, rb = i >> 10;
      int row = rb * 16 + (lane & 15);
      int k   = ks * 32 + (lane >> 4) * 8 + j;
      float w = 0.f;
      if (row < 64) {
        w = Ww[(size_t)k * 64 + row];
      } else if (row < 72) {
        int jj = row - 64;
        const float* ac = (jj < 4) ? (aw + jj) : (aw + 256 + (jj - 4));
        float s = 0.f;
        for (int c = 0; c < 64; ++c) s = fmaf(Ww[(size_t)k * 64 + c], ac[c * 4], s);
        w = s;
      }
      unsigned short hh = f2bf(w);
      AhL[i] = hh;
      AlL[i] = f2bf(w - bf2f(hh));
    }
    if (t < 80) {
      float bb = 0.f;
      if (t < 64) {
        bb = Wb[t];
      } else if (t < 72) {
        int jj = t - 64;
        const float* ac = (jj < 4) ? (aw + jj) : (aw + 256 + (jj - 4));
        float s = 0.f;
        for (int c = 0; c < 64; ++c) s = fmaf(Wb[c], ac[c * 4], s);
        bb = s;
      }
      bcL[t] = bb;
    }
    __syncthreads();

    const int lane = t & 63;
    const int wv   = t >> 6;
    const int col  = lane & 15;
    const int quad = lane >> 4;

    const float4 bc0 = *(const float4*)(bcL +  0 + quad * 4);
    const float4 bc1 = *(const float4*)(bcL + 16 + quad * 4);
    const float4 bc2 = *(const float4*)(bcL + 32 + quad * 4);
    const float4 bc3 = *(const float4*)(bcL + 48 + quad * 4);
    const float4 bc4 = *(const float4*)(bcL + 64 + quad * 4);

    const int base0 = (b - 64) * 256 + wv * 64;
    for (int st = 0; st < 4; ++st) {
      const int node = base0 + st * 16 + col;
      const bool val = (node < N);
      const int nc = val ? node : N - 1;
      const float* xr = x + (size_t)nc * 64 + quad * 8;
      float4 x0 = *(const float4*)(xr);
      float4 x1 = *(const float4*)(xr + 4);
      float4 x2 = *(const float4*)(xr + 32);
      float4 x3 = *(const float4*)(xr + 36);
      bf16x8 bh0, bl0, bh1, bl1;
      split8(x0, x1, &bh0, &bl0);
      split8(x2, x3, &bh1, &bl1);

      f32x4 a0 = {0.f, 0.f, 0.f, 0.f};
      f32x4 a1 = {0.f, 0.f, 0.f, 0.f};
      f32x4 a2 = {0.f, 0.f, 0.f, 0.f};
      f32x4 a3 = {0.f, 0.f, 0.f, 0.f};
      f32x4 a4 = {0.f, 0.f, 0.f, 0.f};
      RBSTEP(a0, 0);
      RBSTEP(a1, 1);
      RBSTEP(a2, 2);
      RBSTEP(a3, 3);
      RBSTEP(a4, 4);

      if (val) {
        unsigned short* hr = h16 + (size_t)node * 64 + quad * 4;
        uint2 w0, w1, w2, w3;
        w0.x = pk(a0[0] + bc0.x, a0[1] + bc0.y);
        w0.y = pk(a0[2] + bc0.z, a0[3] + bc0.w);
        w1.x = pk(a1[0] + bc1.x, a1[1] + bc1.y);
        w1.y = pk(a1[2] + bc1.z, a1[3] + bc1.w);
        w2.x = pk(a2[0] + bc2.x, a2[1] + bc2.y);
        w2.y = pk(a2[2] + bc2.z, a2[3] + bc2.w);
        w3.x = pk(a3[0] + bc3.x, a3[1] + bc3.y);
        w3.y = pk(a3[2] + bc3.z, a3[3] + bc3.w);
        *(uint2*)(hr)      = w0;
        *(uint2*)(hr + 16) = w1;
        *(uint2*)(hr + 32) = w2;
        *(uint2*)(hr + 48) = w3;
        if (quad == 0)
          u[node] = make_float4(a4[0] + bc4.x, a4[1] + bc4.y, a4[2] + bc4.z, a4[3] + bc4.w);
        else if (quad == 1)
          v[node] = make_float4(a4[0] + bc4.x, a4[1] + bc4.y, a4[2] + bc4.z, a4[3] + bc4.w);
      }
    }
    return;
  }

  // ---- per-chunk bin histogram (native INT LDS atomics) ----
  const int cb = b - 64 - NBn;
  for (int i = t; i < NBIN; i += 256) hist[i] = 0;
  __syncthreads();
  const int base = cb * CHUNK + t * 8;
  const int* dptr = ei + E;
  if (base + 7 < E) {
    int4 d0 = *(const int4*)(dptr + base);
    int4 d1 = *(const int4*)(dptr + base + 4);
    atomicAdd(&hist[d0.x >> BINSH], 1);
    atomicAdd(&hist[d0.y >> BINSH], 1);
    atomicAdd(&hist[d0.z >> BINSH], 1);
    atomicAdd(&hist[d0.w >> BINSH], 1);
    atomicAdd(&hist[d1.x >> BINSH], 1);
    atomicAdd(&hist[d1.y >> BINSH], 1);
    atomicAdd(&hist[d1.z >> BINSH], 1);
    atomicAdd(&hist[d1.w >> BINSH], 1);
  } else {
    for (int e = base; e < E; ++e) atomicAdd(&hist[dptr[e] >> BINSH], 1);
  }
  __syncthreads();
  for (int i = t; i < NBIN; i += 256)
    histM[(size_t)cb * NBIN + i] = hist[i];
}

// ------- tile scan pass 1: in-place prefix over CTW chunks, coalesced ------
__global__ __launch_bounds__(256) void k_cs1(int* __restrict__ histM,
    int* __restrict__ tiletot, int NBIN, int NCH, int NBB)
{
  const int ct = blockIdx.x / NBB;
  const int bb = blockIdx.x - ct * NBB;
  const int bin = bb * 256 + threadIdx.x;
  if (bin >= NBIN) return;
  const int b0 = ct * CTW;
  const int b1 = min(b0 + CTW, NCH);
  int run = 0;
  for (int b = b0; b < b1; ++b) {
    size_t idx = (size_t)b * NBIN + bin;
    int v = histM[idx];
    histM[idx] = run;
    run += v;
  }
  tiletot[(size_t)ct * NBIN + bin] = run;
}

// ------- single-block: column prefix of tiletot + bin base scan ------------
__global__ __launch_bounds__(1024) void k_binoff(int* __restrict__ tiletot,
    int* __restrict__ binbase, int NBIN, int NCT, int E)
{
  __shared__ int lds[1024];
  const int t = threadIdx.x;
  const int b0 = t * 4;
  int tot[4];
  #pragma unroll
  for (int k = 0; k < 4; ++k) {
    const int bin = b0 + k;
    int vv[MAXCT];
    #pragma unroll
    for (int ct = 0; ct < MAXCT; ++ct)
      vv[ct] = (ct < NCT && bin < NBIN) ? tiletot[(size_t)ct * NBIN + bin] : 0;
    int run = 0;
    #pragma unroll
    for (int ct = 0; ct < MAXCT; ++ct) { int xx = vv[ct]; vv[ct] = run; run += xx; }
    #pragma unroll
    for (int ct = 0; ct < MAXCT; ++ct)
      if (ct < NCT && bin < NBIN) tiletot[(size_t)ct * NBIN + bin] = vv[ct];
    tot[k] = run;
  }
  const int lsum = (tot[0] + tot[1]) + (tot[2] + tot[3]);
  lds[t] = lsum;
  __syncthreads();
  for (int s = 1; s < 1024; s <<= 1) {
    int a = (t >= s) ? lds[t - s] : 0;
    __syncthreads();
    lds[t] += a;
    __syncthreads();
  }
  int run = lds[t] - lsum;                 // exclusive over threads
  #pragma unroll
  for (int k = 0; k < 4; ++k) {
    const int bin = b0 + k;
    if (bin < NBIN) binbase[bin] = run;
    run += tot[k];
  }
  if (t == 1023) binbase[NBIN] = E;
}

// -------- fill: score + deterministic binned placement (LDS int cursors) ---
__global__ __launch_bounds__(256) void k_fill2(const int* __restrict__ ei,
    const float* __restrict__ et, const int* __restrict__ ctime,
    const float* __restrict__ drate, const float4* __restrict__ u,
    const float4* __restrict__ v, const float* __restrict__ attn_b,
    const int* __restrict__ binbase, const int* __restrict__ tiletot,
    const int* __restrict__ histM, int4* __restrict__ csr, int E, int NBIN)
{
  __shared__ int cur[MAXBIN];
  const int cb = blockIdx.x;
  const int ct = cb / CTW;
  for (int i = threadIdx.x; i < NBIN; i += 256)
    cur[i] = binbase[i] + tiletot[(size_t)ct * NBIN + i]
           + histM[(size_t)cb * NBIN + i];
  __syncthreads();

  const float4 ab = *(const float4*)attn_b;
  const float lam = log1pf(__expf(drate[0]));
  const float ctf = (float)ctime[0];
  const int base = cb * CHUNK + threadIdx.x * 8;

  auto doedge = [&](int s, int d, float tv) {
    const float4 us = u[s];
    const float4 vd = v[d];
    const float w = __expf(-lam * (ctf - tv));
    float4 o; float t;
    t = us.x + vd.x + ab.x; t = (t > 0.f ? t : 0.2f * t) * w; o.x = __expf(t);
    t = us.y + vd.y + ab.y; t = (t > 0.f ? t : 0.2f * t) * w; o.y = __expf(t);
    t = us.z + vd.z + ab.z; t = (t > 0.f ? t : 0.2f * t) * w; o.z = __expf(t);
    t = us.w + vd.w + ab.w; t = (t > 0.f ? t : 0.2f * t) * w; o.w = __expf(t);
    int slot = atomicAdd(&cur[d >> BINSH], 1);      // INT LDS atomic (native)
    int4 rec;
    rec.x = s;
    rec.y = (int)pk(o.x, o.y);
    rec.z = (int)pk(o.z, o.w);
    rec.w = d & (BINSZ - 1);
    csr[slot] = rec;
  };

  if (base + 7 < E) {
    int4 s0 = *(const int4*)(ei + base);
    int4 s1 = *(const int4*)(ei + base + 4);
    int4 d0 = *(const int4*)(ei + E + base);
    int4 d1 = *(const int4*)(ei + E + base + 4);
    float4 t0 = *(const float4*)(et + base);
    float4 t1 = *(const float4*)(et + base + 4);
    doedge(s0.x, d0.x, t0.x);
    doedge(s0.y, d0.y, t0.y);
    doedge(s0.z, d0.z, t0.z);
    doedge(s0.w, d0.w, t0.w);
    doedge(s1.x, d1.x, t1.x);
    doedge(s1.y, d1.y, t1.y);
    doedge(s1.z, d1.z, t1.z);
    doedge(s1.w, d1.w, t1.w);
  } else {
    for (int e = base; e < E; ++e) doedge(ei[e], ei[E + e], et[e]);
  }
}

// -------- in-place node-sort within each bin + per-node CSR offsets --------
__global__ __launch_bounds__(256) void k_sortb(const int* __restrict__ binbase,
    int4* __restrict__ csr, int* __restrict__ offs, int N, int E, int NBIN)
{
  __shared__ int hcnt[BINSZ];
  __shared__ int nbase[BINSZ + 1];
  __shared__ int cur[BINSZ];

  const int bin = blockIdx.x;
  const int start = binbase[bin];
  const int end0  = binbase[bin + 1];
  const int cnt = min(end0 - start, MAXREC);

  if (threadIdx.x < BINSZ) hcnt[threadIdx.x] = 0;
  __syncthreads();

  // read phase: stage up to 4 records per thread into registers
  int4 r0 = {0,0,0,0}, r1 = {0,0,0,0}, r2 = {0,0,0,0}, r3 = {0,0,0,0};
  const int i0 = threadIdx.x, i1 = i0 + 256, i2 = i0 + 512, i3 = i0 + 768;
  const bool b0 = i0 < cnt, b1 = i1 < cnt, b2 = i2 < cnt, b3 = i3 < cnt;
  if (b0) { r0 = csr[start + i0]; atomicAdd(&hcnt[r0.w], 1); }
  if (b1) { r1 = csr[start + i1]; atomicAdd(&hcnt[r1.w], 1); }
  if (b2) { r2 = csr[start + i2]; atomicAdd(&hcnt[r2.w], 1); }
  if (b3) { r3 = csr[start + i3]; atomicAdd(&hcnt[r3.w], 1); }
  __syncthreads();                        // all reads done before any write

  if (threadIdx.x == 0) {
    int run = 0;
    #pragma unroll
    for (int i = 0; i < BINSZ; ++i) { nbase[i] = run; cur[i] = run; run += hcnt[i]; }
    nbase[BINSZ] = run;
  }
  __syncthreads();

  if (threadIdx.x < BINSZ) {
    int n = bin * BINSZ + threadIdx.x;
    if (n < N) offs[n] = start + nbase[threadIdx.x];
  }
  if (bin == 0 && threadIdx.x == 255) offs[N] = E;

  // write phase: scatter back sorted (disjoint region per block)
  if (b0) csr[start + atomicAdd(&cur[r0.w], 1)] = r0;
  if (b1) csr[start + atomicAdd(&cur[r1.w], 1)] = r1;
  if (b2) csr[start + atomicAdd(&cur[r2.w], 1)] = r2;
  if (b3) csr[start + atomicAdd(&cur[r3.w], 1)] = r3;
}

// -------- aggregation: wave/node, pipelined 4-edge groups (r6 winner) ------
__global__ __launch_bounds__(256) void k_agg(const unsigned short* __restrict__ h16,
    const int4* __restrict__ csr, const int* __restrict__ offs,
    unsigned short* __restrict__ agg, int N)
{
  const int c = threadIdx.x & 63;
  const int wid = blockIdx.x * 4 + (threadIdx.x >> 6);
  const int wstride = gridDim.x * 4;

  for (int n0 = wid; n0 < N; n0 += wstride) {
    const int n = __builtin_amdgcn_readfirstlane(n0);
    const int p0 = offs[n];
    const int p1 = offs[n + 1];
    const int nf = (p1 - p0) & ~3;                  // full-group edge count

    float acc0 = 0.f, acc1 = 0.f, acc2 = 0.f, acc3 = 0.f;
    float den0 = 0.f, den1 = 0.f, den2 = 0.f, den3 = 0.f;

    int4 rA0, rA1, rA2, rA3;                        // records: uniform s_loads
    float gA0 = 0.f, gA1 = 0.f, gA2 = 0.f, gA3 = 0.f;
    if (nf) {
      rA0 = csr[p0];     rA1 = csr[p0 + 1];
      rA2 = csr[p0 + 2]; rA3 = csr[p0 + 3];
      gA0 = bf2f(h16[(size_t)rA0.x * 64 + c]);
      gA1 = bf2f(h16[(size_t)rA1.x * 64 + c]);
      gA2 = bf2f(h16[(size_t)rA2.x * 64 + c]);
      gA3 = bf2f(h16[(size_t)rA3.x * 64 + c]);
    }
    for (int p = p0; p < p0 + nf; p += 4) {
      int4 rB0, rB1, rB2, rB3;
      float gB0, gB1, gB2, gB3;
      const bool more = (p + 4 < p0 + nf);
      if (more) {                                   // prefetch next group
        rB0 = csr[p + 4]; rB1 = csr[p + 5];
        rB2 = csr[p + 6]; rB3 = csr[p + 7];
        gB0 = bf2f(h16[(size_t)rB0.x * 64 + c]);
        gB1 = bf2f(h16[(size_t)rB1.x * 64 + c]);
        gB2 = bf2f(h16[(size_t)rB2.x * 64 + c]);
        gB3 = bf2f(h16[(size_t)rB3.x * 64 + c]);
      }
      // scalar unpack of bf16 es (wave-uniform)
      float e00 = bflo(rA0.y), e01 = bfhi(rA0.y), e02 = bflo(rA0.z), e03 = bfhi(rA0.z);
      float e10 = bflo(rA1.y), e11 = bfhi(rA1.y), e12 = bflo(rA1.z), e13 = bfhi(rA1.z);
      float e20 = bflo(rA2.y), e21 = bfhi(rA2.y), e22 = bflo(rA2.z), e23 = bfhi(rA2.z);
      float e30 = bflo(rA3.y), e31 = bfhi(rA3.y), e32 = bflo(rA3.z), e33 = bfhi(rA3.z);
      den0 += (e00 + e10) + (e20 + e30);
      den1 += (e01 + e11) + (e21 + e31);
      den2 += (e02 + e12) + (e22 + e32);
      den3 += (e03 + e13) + (e23 + e33);
      acc0 = fmaf(e00, gA0, fmaf(e10, gA1, fmaf(e20, gA2, fmaf(e30, gA3, acc0))));
      acc1 = fmaf(e01, gA0, fmaf(e11, gA1, fmaf(e21, gA2, fmaf(e31, gA3, acc1))));
      acc2 = fmaf(e02, gA0, fmaf(e12, gA1, fmaf(e22, gA2, fmaf(e32, gA3, acc2))));
      acc3 = fmaf(e03, gA0, fmaf(e13, gA1, fmaf(e23, gA2, fmaf(e33, gA3, acc3))));
      if (more) {
        rA0 = rB0; rA1 = rB1; rA2 = rB2; rA3 = rB3;
        gA0 = gB0; gA1 = gB1; gA2 = gB2; gA3 = gB3;
      }
    }
    for (int p = p0 + nf; p < p1; ++p) {            // tail (<=3, wave-uniform)
      int4 r = csr[p];
      float g = bf2f(h16[(size_t)r.x * 64 + c]);
      float e0 = bflo(r.y), e1 = bfhi(r.y), e2 = bflo(r.z), e3 = bfhi(r.z);
      den0 += e0; den1 += e1; den2 += e2; den3 += e3;
      acc0 = fmaf(e0, g, acc0);
      acc1 = fmaf(e1, g, acc1);
      acc2 = fmaf(e2, g, acc2);
      acc3 = fmaf(e3, g, acc3);
    }
    uint2 w;
    w.x = pk(acc0 / (den0 + 1e-8f), acc1 / (den1 + 1e-8f));
    w.y = pk(acc2 / (den2 + 1e-8f), acc3 / (den3 + 1e-8f));
    *(uint2*)(agg + (size_t)n * 256 + c * 4) = w;   // coalesced b64
  }
}

// ------- proj GEMM via MFMA + fused residual/LN/ReLU epilogue -------------
__global__ __launch_bounds__(256) void k_projm(const unsigned short* __restrict__ agg,
    const unsigned short* __restrict__ Bf, const float* __restrict__ x,
    const float* __restrict__ Pb,
    const float* __restrict__ lg, const float* __restrict__ lb,
    float* __restrict__ out, int N)
{
  const int lane = threadIdx.x & 63;
  const int wv = threadIdx.x >> 6;
  const int nt = blockIdx.x * 4 + wv;           // 16-node tile index
  if (nt * 16 >= N) return;
  const int col  = lane & 15;
  const int quad = lane >> 4;
  const int base = nt * 16;

  int na = base + col; if (na >= N) na = N - 1;
  const unsigned short* aptr = agg + (size_t)na * 256 + quad * 8;

  f32x4 acc0 = {0.f, 0.f, 0.f, 0.f};
  f32x4 acc1 = {0.f, 0.f, 0.f, 0.f};
  f32x4 acc2 = {0.f, 0.f, 0.f, 0.f};
  f32x4 acc3 = {0.f, 0.f, 0.f, 0.f};

  #pragma unroll
  for (int ks = 0; ks < 8; ++ks) {
    bf16x8 av = *(const bf16x8*)(aptr + ks * 32);
    bf16x8 b0 = *(const bf16x8*)(Bf + ((size_t)(ks * 4 + 0) * 64 + lane) * 8);
    bf16x8 b1 = *(const bf16x8*)(Bf + ((size_t)(ks * 4 + 1) * 64 + lane) * 8);
    bf16x8 b2 = *(const bf16x8*)(Bf + ((size_t)(ks * 4 + 2) * 64 + lane) * 8);
    bf16x8 b3 = *(const bf16x8*)(Bf + ((size_t)(ks * 4 + 3) * 64 + lane) * 8);
    acc0 = __builtin_amdgcn_mfma_f32_16x16x32_bf16(av, b0, acc0, 0, 0, 0);
    acc1 = __builtin_amdgcn_mfma_f32_16x16x32_bf16(av, b1, acc1, 0, 0, 0);
    acc2 = __builtin_amdgcn_mfma_f32_16x16x32_bf16(av, b2, acc2, 0, 0, 0);
    acc3 = __builtin_amdgcn_mfma_f32_16x16x32_bf16(av, b3, acc3, 0, 0, 0);
  }

  const float pb0 = Pb[col], pb1 = Pb[16 + col], pb2 = Pb[32 + col], pb3 = Pb[48 + col];
  float v[4][4];                                 // [cb][reg]
  #pragma unroll
  for (int r = 0; r < 4; ++r) {
    int node = base + quad * 4 + r; if (node >= N) node = N - 1;
    const float* xr = x + (size_t)node * 64;
    v[0][r] = acc0[r] + pb0 + xr[col];
    v[1][r] = acc1[r] + pb1 + xr[16 + col];
    v[2][r] = acc2[r] + pb2 + xr[32 + col];
    v[3][r] = acc3[r] + pb3 + xr[48 + col];
  }

  float mu[4], inv[4];
  #pragma unroll
  for (int r = 0; r < 4; ++r) {
    float s = (v[0][r] + v[1][r]) + (v[2][r] + v[3][r]);
    s += __shfl_xor(s, 1, 64); s += __shfl_xor(s, 2, 64);
    s += __shfl_xor(s, 4, 64); s += __shfl_xor(s, 8, 64);
    mu[r] = s * 0.015625f;
  }
  #pragma unroll
  for (int r = 0; r < 4; ++r) {
    float d0 = v[0][r] - mu[r], d1 = v[1][r] - mu[r];
    float d2 = v[2][r] - mu[r], d3 = v[3][r] - mu[r];
    float s = fmaf(d0, d0, d1 * d1) + fmaf(d2, d2, d3 * d3);
    s += __shfl_xor(s, 1, 64); s += __shfl_xor(s, 2, 64);
    s += __shfl_xor(s, 4, 64); s += __shfl_xor(s, 8, 64);
    inv[r] = rsqrtf(s * 0.015625f + 1e-5f);
  }

  const float lg0 = lg[col], lg1 = lg[16 + col], lg2 = lg[32 + col], lg3 = lg[48 + col];
  const float lb0 = lb[col], lb1 = lb[16 + col], lb2 = lb[32 + col], lb3 = lb[48 + col];
  #pragma unroll
  for (int r = 0; r < 4; ++r) {
    int node = base + quad * 4 + r;
    if (node < N) {
      float* orow = out + (size_t)node * 64;
      orow[col]      = fmaxf(fmaf(lg0 * (v[0][r] - mu[r]), inv[r], lb0), 0.f);
      orow[16 + col] = fmaxf(fmaf(lg1 * (v[1][r] - mu[r]), inv[r], lb1), 0.f);
      orow[32 + col] = fmaxf(fmaf(lg2 * (v[2][r] - mu[r]), inv[r], lb2), 0.f);
      orow[48 + col] = fmaxf(fmaf(lg3 * (v[3][r] - mu[r]), inv[r], lb3), 0.f);
    }
  }
}

// ---------------------------------------------------------------------------
extern "C" void kernel_launch(void* const* d_in, const int* in_sizes, int n_in,
                              void* d_out, int out_size, void* d_ws, size_t ws_size,
                              hipStream_t stream)
{
  const float* x  = (const float*)d_in[0];
  const int*   ei = (const int*)d_in[1];
  const float* et = (const float*)d_in[2];
  const int*   ct = (const int*)d_in[3];
  const float* Ww = (const float*)d_in[4];
  const float* Wb = (const float*)d_in[5];
  const float* aw = (const float*)d_in[6];
  const float* ab = (const float*)d_in[7];
  const float* dr = (const float*)d_in[8];
  const float* Pw = (const float*)d_in[9];
  const float* Pb = (const float*)d_in[10];
  const float* lg = (const float*)d_in[11];
  const float* lb = (const float*)d_in[12];
  float* out = (float*)d_out;

  const int N = in_sizes[0] / 64;
  const int E = in_sizes[2];
  const int NBIN = (N + BINSZ - 1) >> BINSH;
  const int NCH  = (E + CHUNK - 1) / CHUNK;       // histogram/scatter chunks
  const int NCT  = (NCH + CTW - 1) / CTW;         // scan tiles along chunks
  const int NBB  = (NBIN + 255) / 256;            // blocks over bins
  const int NBn  = (N + 255) / 256;               // node blocks

  char* ws = (char*)d_ws;
  size_t off = 0;
  auto take = [&](size_t bytes) -> char* {
    char* p = ws + off;
    off = (off + bytes + 255) & ~(size_t)255;
    return p;
  };
  unsigned short* h16 = (unsigned short*)take((size_t)N * 64 * 2);
  int4*   csr    = (int4*)take((size_t)E * 16);
  unsigned short* agg = (unsigned short*)take((size_t)N * 256 * 2);
  float4* u      = (float4*)take((size_t)N * 16);
  float4* v      = (float4*)take((size_t)N * 16);
  unsigned short* Bf = (unsigned short*)take(16384 * 2);
  int*    histM  = (int*)take((size_t)NCH * NBIN * 4);
  int*    tiletot= (int*)take((size_t)NCT * NBIN * 4);
  int*    binbase= (int*)take(((size_t)NBIN + 1) * 4);
  int*    offs   = (int*)take(((size_t)N + 1) * 4);

  k_inith<<<64 + NBn + NCH, 256, 0, stream>>>(Pw, Ww, Wb, aw, ei, x, Bf, h16, u, v,
                                              histM, N, E, NBn, NBIN);
  k_cs1<<<NCT * NBB, 256, 0, stream>>>(histM, tiletot, NBIN, NCH, NBB);
  k_binoff<<<1, 1024, 0, stream>>>(tiletot, binbase, NBIN, NCT, E);
  k_fill2<<<NCH, 256, 0, stream>>>(ei, et, ct, dr, u, v, ab, binbase, tiletot, histM, csr, E, NBIN);
  k_sortb<<<NBIN, 256, 0, stream>>>(binbase, csr, offs, N, E, NBIN);
  k_agg<<<2048, 256, 0, stream>>>(h16, csr, offs, agg, N);
  const int NT = (N + 15) / 16;
  k_projm<<<(NT + 3) / 4, 256, 0, stream>>>(agg, Bf, x, Pb, lg, lb, out, N);
}